// Round 5
// baseline (1647.696 us; speedup 1.0000x reference)
//
#include <hip/hip_runtime.h>

#define N_NODES 4096
#define C_CH    128
#define NSPEC   10
#define NCUB    165
#define NQUAD   45
#define NMONO   219   // 165 cubic + 45 quad + 9 linear

// ---- workspace layout (bytes) ----
#define WS_CNTOFF 0
#define WS_GLIST  256                       // 4096 ints = 16384
#define WS_U3SYM  16640                     // 4og*165*4k floats = 10560
#define WS_U2SYM  27200                     // 4og*45*2k  floats = 1440
#define WS_COEFF  28672                     // 1280*876 floats = 4485120
#define WS_XG     4513792                   // 1152*4096 floats = 18874368
#define WS_FG     23388160                  // 512*4096 floats  = 8388608
// total ~31.8 MB

// ---------------------------------------------------------------------------
// Kernel A: fused prep (blocks 0-7) + species sort (block 8).
// ---------------------------------------------------------------------------
__global__ __launch_bounds__(512) void k_a(const float* __restrict__ U3_0e,
        const float* __restrict__ U3_1o, const float* __restrict__ U2_0e,
        const float* __restrict__ U2_1o, const int* __restrict__ specie,
        int* __restrict__ cntoff, int* __restrict__ glist,
        float* __restrict__ U3sym, float* __restrict__ U2sym) {
    __shared__ int lcnt[NSPEC], lcur[NSPEC];
    int t = threadIdx.x;
    if (blockIdx.x == 8) {                  // ---- sort ----
        if (t < NSPEC) lcnt[t] = 0;
        __syncthreads();
        int ss[8];
        #pragma unroll
        for (int r = 0; r < 8; r++) {
            ss[r] = specie[r * 512 + t];
            atomicAdd(&lcnt[ss[r]], 1);
        }
        __syncthreads();
        if (t == 0) {
            int acc = 0;
            for (int s = 0; s < NSPEC; s++) {
                lcur[s] = acc; cntoff[16 + s] = acc; cntoff[s] = lcnt[s]; acc += lcnt[s];
            }
        }
        __syncthreads();
        #pragma unroll
        for (int r = 0; r < 8; r++) {
            int pos = atomicAdd(&lcur[ss[r]], 1);
            glist[pos] = r * 512 + t;
        }
        return;
    }
    // ---- prep: symmetrize U3/U2 ----
    int task = blockIdx.x * 512 + t;
    if (task >= 2640 + 360) return;
    if (task < 2640) {               // cubic: og(4) * m(165) * k(4)
        int og = task / 660;
        int r  = task - og * 660;
        int m  = r >> 2, k = r & 3;
        int a = 0, b = 0, d = 0;
        {   int idx = 0;
            for (int a0 = 0; a0 < 9; a0++)
                for (int b0 = a0; b0 < 9; b0++)
                    for (int d0 = b0; d0 < 9; d0++) {
                        if (idx == m) { a = a0; b = b0; d = d0; }
                        idx++;
                    }
        }
        const float* U3 = (og == 0) ? U3_0e : U3_1o;
        int o = (og == 0) ? 0 : og - 1;
        const float* Ub = U3 + (size_t)o * 2916;   // [p][q][i][k] strides 324/36/4/1
        #define U3AT(p,q,i) Ub[((p)*9+(q))*36 + (i)*4 + k]
        float sum = U3AT(a,b,d) + U3AT(a,d,b) + U3AT(b,a,d)
                  + U3AT(b,d,a) + U3AT(d,a,b) + U3AT(d,b,a);
        #undef U3AT
        float sc = (a == b && b == d) ? (1.f/6.f)
                 : ((a == b || b == d || a == d) ? 0.5f : 1.f);
        U3sym[(og * 165 + m) * 4 + k] = sum * sc;
    } else {                          // quad: og(4) * q(45) * k(2)
        int t2 = task - 2640;
        int og = t2 / 90;
        int r  = t2 - og * 90;
        int q  = r >> 1, k = r & 1;
        int a = 0, b = 0;
        {   int idx = 0;
            for (int a0 = 0; a0 < 9; a0++)
                for (int b0 = a0; b0 < 9; b0++) { if (idx == q) { a = a0; b = b0; } idx++; }
        }
        const float* U2 = (og == 0) ? U2_0e : U2_1o;
        int o = (og == 0) ? 0 : og - 1;
        const float* Ub = U2 + (size_t)o * 162;    // [p][i][k] strides 18/2/1
        float sum = Ub[(a*9 + b)*2 + k] + Ub[(b*9 + a)*2 + k];
        if (a == b) sum *= 0.5f;
        U2sym[(og * 45 + q) * 2 + k] = sum;
    }
}

// ---------------------------------------------------------------------------
// Kernel B: fused coeff (blocks 0-1279) + gather/transpose (blocks 1280-2431).
// coeff layout: [s*128+c][mono 0..218][og 0..3]
// xg layout: [ci 0..1151][slot 0..4095], slot = species-sorted order.
// ---------------------------------------------------------------------------
__global__ __launch_bounds__(256) void k_b(const float* __restrict__ U3sym,
        const float* __restrict__ U2sym,
        const float* __restrict__ U1_0e, const float* __restrict__ U1_1o,
        const float* __restrict__ W3_0e, const float* __restrict__ W3_1o,
        const float* __restrict__ W2_0e, const float* __restrict__ W2_1o,
        const float* __restrict__ W1_0e, const float* __restrict__ W1_1o,
        float* __restrict__ coeff,
        const float* __restrict__ x, const int* __restrict__ glist,
        float* __restrict__ xg) {
    __shared__ float tile[64][65];
    __shared__ int nodes[64];
    int bx = blockIdx.x;
    if (bx < 1280) {                       // ---- coeff ----
        int s = bx >> 7, c = bx & 127;
        for (int t = threadIdx.x; t < NMONO * 4; t += 256) {
            int m = t >> 2, og = t & 3;
            float val;
            if (m < NCUB) {
                const float* W3 = (og == 0) ? W3_0e : W3_1o;   // [s][k][c]
                const float* u  = U3sym + (og * 165 + m) * 4;
                val = u[0] * W3[s*512 +       c] + u[1] * W3[s*512 + 128 + c]
                    + u[2] * W3[s*512 + 256 + c] + u[3] * W3[s*512 + 384 + c];
            } else if (m < NCUB + NQUAD) {
                int q = m - NCUB;
                const float* W2 = (og == 0) ? W2_0e : W2_1o;   // [s][k][c]
                const float* u  = U2sym + (og * 45 + q) * 2;
                val = u[0] * W2[s*256 + c] + u[1] * W2[s*256 + 128 + c];
            } else {
                int l = m - (NCUB + NQUAD);
                const float* U1 = (og == 0) ? U1_0e : U1_1o;   // [o][i][k=1]
                const float* W1 = (og == 0) ? W1_0e : W1_1o;   // [s][1][c]
                int o = (og == 0) ? 0 : og - 1;
                val = U1[o * 9 + l] * W1[s * 128 + c];
            }
            coeff[(size_t)bx * 876 + t] = val;
        }
        return;
    }
    // ---- gather ----
    int b2 = bx - 1280;
    int st = b2 / 18, ct = b2 - st * 18;   // slot-tile(64 slots), ci-tile(64 of 1152)
    int t = threadIdx.x;
    if (t < 64) nodes[t] = glist[st * 64 + t];
    __syncthreads();
    #pragma unroll
    for (int r = 0; r < 4; ++r) {          // 64 sl x 16 float4
        int flat = r * 256 + t;
        int sl = flat >> 4, q = flat & 15;
        float4 v = *(const float4*)&x[(size_t)nodes[sl] * 1152 + ct * 64 + q * 4];
        tile[sl][q * 4 + 0] = v.x; tile[sl][q * 4 + 1] = v.y;
        tile[sl][q * 4 + 2] = v.z; tile[sl][q * 4 + 3] = v.w;
    }
    __syncthreads();
    #pragma unroll
    for (int r = 0; r < 16; ++r) {
        int flat = r * 256 + t;
        int ci = flat >> 6, sl = flat & 63;
        xg[(size_t)(ct * 64 + ci) * 4096 + st * 64 + sl] = tile[sl][ci];
    }
}

// ---------------------------------------------------------------------------
// Kernel 5: main contraction. Block=(s,c).
// Coefficients staged ONCE into LDS (coalesced float4), read in the loop as
// LDS BROADCASTS (uniform address, conflict-free). sched_barrier(0) after
// every (a,b)-group caps in-flight ds_read_b128 at ~11 (44 VGPRs) — this is
// what prevents the rounds-2/3 spill (scheduler hoisted all 219 reads,
// wanted 876 VGPRs, spilled 1.2 GB to scratch). Round 4 (global scalar
// coeff path) was latency-bound at 180us: 876 s_load dwords consumed in ONE
// pass per block, occupancy 10%, nothing hides the chain. DO NOT add a
// min-waves arg to __launch_bounds__ (round 2: caps VGPR -> spill).
// ---------------------------------------------------------------------------
__global__ __launch_bounds__(256) void k_main(const float* __restrict__ xg,
        const int* __restrict__ cntoff, const float* __restrict__ coeff,
        float* __restrict__ fg) {
    __shared__ __align__(16) float cfs[880];
    int blk = blockIdx.x;
    int s = blk >> 7, c = blk & 127;
    const float* __restrict__ cf = coeff + (size_t)blk * 876;
    {   // coalesced float4 staging: 219 vec4 < 256 threads -> one round
        int t = threadIdx.x;
        if (t < 219) ((float4*)cfs)[t] = ((const float4*)cf)[t];
    }
    int n   = cntoff[s];
    int off = cntoff[16 + s];
    __syncthreads();
    if (n == 0) return;

    for (int base = 0; base < n; base += 512) {
        int i0 = base + (int)threadIdx.x;
        int i1 = i0 + 256;
        int j0 = off + min(i0, n - 1);
        int j1 = off + min(i1, n - 1);
        float x0[9], x1[9];
        #pragma unroll
        for (int i = 0; i < 9; i++) {
            const float* row = xg + (size_t)(c * 9 + i) * 4096;
            x0[i] = row[j0];
            x1[i] = row[j1];
        }
        float a0[4] = {0.f,0.f,0.f,0.f}, a1[4] = {0.f,0.f,0.f,0.f};
        int m3 = 0, m2 = 0;
        #pragma unroll
        for (int a = 0; a < 9; a++) {
            {   // linear term
                float4 cl = *(const float4*)&cfs[(210 + a) * 4];
                a0[0] = fmaf(cl.x, x0[a], a0[0]); a1[0] = fmaf(cl.x, x1[a], a1[0]);
                a0[1] = fmaf(cl.y, x0[a], a0[1]); a1[1] = fmaf(cl.y, x1[a], a1[1]);
                a0[2] = fmaf(cl.z, x0[a], a0[2]); a1[2] = fmaf(cl.z, x1[a], a1[2]);
                a0[3] = fmaf(cl.w, x0[a], a0[3]); a1[3] = fmaf(cl.w, x1[a], a1[3]);
            }
            #pragma unroll
            for (int b = a; b < 9; b++) {
                float p0 = x0[a] * x0[b], p1 = x1[a] * x1[b];
                float4 cq = *(const float4*)&cfs[(165 + m2) * 4]; m2++;
                a0[0] = fmaf(cq.x, p0, a0[0]); a1[0] = fmaf(cq.x, p1, a1[0]);
                a0[1] = fmaf(cq.y, p0, a0[1]); a1[1] = fmaf(cq.y, p1, a1[1]);
                a0[2] = fmaf(cq.z, p0, a0[2]); a1[2] = fmaf(cq.z, p1, a1[2]);
                a0[3] = fmaf(cq.w, p0, a0[3]); a1[3] = fmaf(cq.w, p1, a1[3]);
                #pragma unroll
                for (int d = b; d < 9; d++) {
                    float4 c3 = *(const float4*)&cfs[m3 * 4]; m3++;
                    float q0 = p0 * x0[d], q1 = p1 * x1[d];
                    a0[0] = fmaf(c3.x, q0, a0[0]); a1[0] = fmaf(c3.x, q1, a1[0]);
                    a0[1] = fmaf(c3.y, q0, a0[1]); a1[1] = fmaf(c3.y, q1, a1[1]);
                    a0[2] = fmaf(c3.z, q0, a0[2]); a1[2] = fmaf(c3.z, q1, a1[2]);
                    a0[3] = fmaf(c3.w, q0, a0[3]); a1[3] = fmaf(c3.w, q1, a1[3]);
                }
                __builtin_amdgcn_sched_barrier(0);  // cap ds_read hoisting
            }
        }
        if (i0 < n) {
            #pragma unroll
            for (int e = 0; e < 4; e++) fg[(size_t)(e * 128 + c) * 4096 + j0] = a0[e];
        }
        if (i1 < n) {
            #pragma unroll
            for (int e = 0; e < 4; e++) fg[(size_t)(e * 128 + c) * 4096 + j1] = a1[e];
        }
    }
}

// ---------------------------------------------------------------------------
// Kernel 6: epilogue linear. Block=(slot-tile 64, jg 0..7); staging reads are
// fully coalesced from fg; output rows via glist (256B runs per row).
// ---------------------------------------------------------------------------
__global__ __launch_bounds__(256) void k_epi(const float* __restrict__ fg,
        const float* __restrict__ W0, const float* __restrict__ W1,
        const float* __restrict__ bias, const int* __restrict__ glist,
        float* __restrict__ out) {
    __shared__ float smem[128 * 65];
    __shared__ int nodes[64];
    int bx = blockIdx.x;
    int st = bx >> 3, jg = bx & 7;
    int s0 = st * 64;
    int t  = threadIdx.x;
    int o  = jg >> 1;                        // output component 0..3 (uniform)
    if (t < 64) nodes[t] = glist[s0 + t];
    #pragma unroll
    for (int r = 0; r < 32; ++r) {
        int flat = r * 256 + t;              // 8192 = 128c * 64sl
        int c = flat >> 6, sl = flat & 63;
        smem[c * 65 + sl] = fg[(size_t)(o * 128 + c) * 4096 + s0 + sl];
    }
    __syncthreads();

    int w    = __builtin_amdgcn_readfirstlane((int)(t >> 6));
    int lane = t & 63;
    int mb   = (jg & 1) * 64 + w * 16;       // wave's m base (uniform)
    const float* __restrict__ Wsel = (o == 0) ? W0 : W1;

    float acc[16];
    #pragma unroll
    for (int jj = 0; jj < 16; jj++) acc[jj] = 0.f;

    #pragma unroll 4
    for (int c = 0; c < 128; ++c) {
        float fv = smem[c * 65 + lane];
        #pragma unroll
        for (int jj = 0; jj < 16; jj++)
            acc[jj] = fmaf(fv, Wsel[c * 128 + mb + jj], acc[jj]);
    }
    __syncthreads();

    const float scale = 0.08838834764831845f; // 1/sqrt(128)
    #pragma unroll
    for (int jj = 0; jj < 16; jj++) {
        float v = acc[jj] * scale;
        if (o == 0) v += bias[mb + jj];
        smem[(w * 16 + jj) * 65 + lane] = v;  // trbuf[j_local][slot]
    }
    __syncthreads();

    #pragma unroll
    for (int r = 0; r < 16; ++r) {
        int flat = r * 256 + t;               // 4096 = 64j * 64sl
        int jl = flat & 63, nn = flat >> 6;
        int m  = (jg & 1) * 64 + jl;
        int col = (o == 0) ? m : (128 + m * 3 + (o - 1));
        out[(size_t)nodes[nn] * 512 + col] = smem[jl * 65 + nn];
    }
}

extern "C" void kernel_launch(void* const* d_in, const int* in_sizes, int n_in,
                              void* d_out, int out_size, void* d_ws, size_t ws_size,
                              hipStream_t stream) {
    const float* x     = (const float*)d_in[0];
    const int*   spec  = (const int*)  d_in[1];
    const float* U3_0e = (const float*)d_in[2];
    const float* U2_0e = (const float*)d_in[3];
    const float* U1_0e = (const float*)d_in[4];
    const float* W3_0e = (const float*)d_in[5];
    const float* W2_0e = (const float*)d_in[6];
    const float* W1_0e = (const float*)d_in[7];
    const float* U3_1o = (const float*)d_in[8];
    const float* U2_1o = (const float*)d_in[9];
    const float* U1_1o = (const float*)d_in[10];
    const float* W3_1o = (const float*)d_in[11];
    const float* W2_1o = (const float*)d_in[12];
    const float* W1_1o = (const float*)d_in[13];
    const float* Wlin0 = (const float*)d_in[14];
    const float* Wlin1 = (const float*)d_in[15];
    const float* bias0 = (const float*)d_in[16];
    float* out = (float*)d_out;

    char* ws = (char*)d_ws;
    int*   cntoff = (int*)  (ws + WS_CNTOFF);
    int*   glist  = (int*)  (ws + WS_GLIST);
    float* U3sym  = (float*)(ws + WS_U3SYM);
    float* U2sym  = (float*)(ws + WS_U2SYM);
    float* coeff  = (float*)(ws + WS_COEFF);
    float* xg     = (float*)(ws + WS_XG);
    float* fg     = (float*)(ws + WS_FG);
    (void)in_sizes; (void)n_in; (void)out_size; (void)ws_size;

    hipLaunchKernelGGL(k_a,    dim3(9),    dim3(512), 0, stream,
                       U3_0e, U3_1o, U2_0e, U2_1o, spec, cntoff, glist, U3sym, U2sym);
    hipLaunchKernelGGL(k_b,    dim3(2432), dim3(256), 0, stream,
                       U3sym, U2sym, U1_0e, U1_1o, W3_0e, W3_1o,
                       W2_0e, W2_1o, W1_0e, W1_1o, coeff, x, glist, xg);
    hipLaunchKernelGGL(k_main, dim3(1280), dim3(256), 0, stream, xg, cntoff, coeff, fg);
    hipLaunchKernelGGL(k_epi,  dim3(512),  dim3(256), 0, stream, fg, Wlin0, Wlin1, bias0, glist, out);
}

// Round 6
// 1556.534 us; speedup vs baseline: 1.0586x; 1.0586x over previous
//
#include <hip/hip_runtime.h>

#define N_NODES 4096
#define C_CH    128
#define NSPEC   10
#define NCUB    165
#define NQUAD   45
#define NMONO   219   // 165 cubic + 45 quad + 9 linear

// ---- workspace layout (bytes) ----
#define WS_CNTOFF 0
#define WS_GLIST  256                       // 4096 ints = 16384
#define WS_U3SYM  16640                     // 4og*165*4k floats = 10560
#define WS_U2SYM  27200                     // 4og*45*2k  floats = 1440
#define WS_COEFF  28672                     // 1280*876 floats = 4485120
#define WS_XG     4513792                   // 1152*4096 floats = 18874368
#define WS_FG     23388160                  // 512*4096 floats  = 8388608
// total ~31.8 MB

// ---------------------------------------------------------------------------
// Kernel A: fused prep (blocks 0-7) + species sort (block 8).
// ---------------------------------------------------------------------------
__global__ __launch_bounds__(512) void k_a(const float* __restrict__ U3_0e,
        const float* __restrict__ U3_1o, const float* __restrict__ U2_0e,
        const float* __restrict__ U2_1o, const int* __restrict__ specie,
        int* __restrict__ cntoff, int* __restrict__ glist,
        float* __restrict__ U3sym, float* __restrict__ U2sym) {
    __shared__ int lcnt[NSPEC], lcur[NSPEC];
    int t = threadIdx.x;
    if (blockIdx.x == 8) {                  // ---- sort ----
        if (t < NSPEC) lcnt[t] = 0;
        __syncthreads();
        int ss[8];
        #pragma unroll
        for (int r = 0; r < 8; r++) {
            ss[r] = specie[r * 512 + t];
            atomicAdd(&lcnt[ss[r]], 1);
        }
        __syncthreads();
        if (t == 0) {
            int acc = 0;
            for (int s = 0; s < NSPEC; s++) {
                lcur[s] = acc; cntoff[16 + s] = acc; cntoff[s] = lcnt[s]; acc += lcnt[s];
            }
        }
        __syncthreads();
        #pragma unroll
        for (int r = 0; r < 8; r++) {
            int pos = atomicAdd(&lcur[ss[r]], 1);
            glist[pos] = r * 512 + t;
        }
        return;
    }
    // ---- prep: symmetrize U3/U2 ----
    int task = blockIdx.x * 512 + t;
    if (task >= 2640 + 360) return;
    if (task < 2640) {               // cubic: og(4) * m(165) * k(4)
        int og = task / 660;
        int r  = task - og * 660;
        int m  = r >> 2, k = r & 3;
        int a = 0, b = 0, d = 0;
        {   int idx = 0;
            for (int a0 = 0; a0 < 9; a0++)
                for (int b0 = a0; b0 < 9; b0++)
                    for (int d0 = b0; d0 < 9; d0++) {
                        if (idx == m) { a = a0; b = b0; d = d0; }
                        idx++;
                    }
        }
        const float* U3 = (og == 0) ? U3_0e : U3_1o;
        int o = (og == 0) ? 0 : og - 1;
        const float* Ub = U3 + (size_t)o * 2916;   // [p][q][i][k] strides 324/36/4/1
        #define U3AT(p,q,i) Ub[((p)*9+(q))*36 + (i)*4 + k]
        float sum = U3AT(a,b,d) + U3AT(a,d,b) + U3AT(b,a,d)
                  + U3AT(b,d,a) + U3AT(d,a,b) + U3AT(d,b,a);
        #undef U3AT
        float sc = (a == b && b == d) ? (1.f/6.f)
                 : ((a == b || b == d || a == d) ? 0.5f : 1.f);
        U3sym[(og * 165 + m) * 4 + k] = sum * sc;
    } else {                          // quad: og(4) * q(45) * k(2)
        int t2 = task - 2640;
        int og = t2 / 90;
        int r  = t2 - og * 90;
        int q  = r >> 1, k = r & 1;
        int a = 0, b = 0;
        {   int idx = 0;
            for (int a0 = 0; a0 < 9; a0++)
                for (int b0 = a0; b0 < 9; b0++) { if (idx == q) { a = a0; b = b0; } idx++; }
        }
        const float* U2 = (og == 0) ? U2_0e : U2_1o;
        int o = (og == 0) ? 0 : og - 1;
        const float* Ub = U2 + (size_t)o * 162;    // [p][i][k] strides 18/2/1
        float sum = Ub[(a*9 + b)*2 + k] + Ub[(b*9 + a)*2 + k];
        if (a == b) sum *= 0.5f;
        U2sym[(og * 45 + q) * 2 + k] = sum;
    }
}

// ---------------------------------------------------------------------------
// Kernel B: fused coeff (blocks 0-1279) + gather/transpose (blocks 1280-2431).
// coeff layout: [s*128+c][mono 0..218][og 0..3]
// xg layout: [ci 0..1151][slot 0..4095], slot = species-sorted order.
// ---------------------------------------------------------------------------
__global__ __launch_bounds__(256) void k_b(const float* __restrict__ U3sym,
        const float* __restrict__ U2sym,
        const float* __restrict__ U1_0e, const float* __restrict__ U1_1o,
        const float* __restrict__ W3_0e, const float* __restrict__ W3_1o,
        const float* __restrict__ W2_0e, const float* __restrict__ W2_1o,
        const float* __restrict__ W1_0e, const float* __restrict__ W1_1o,
        float* __restrict__ coeff,
        const float* __restrict__ x, const int* __restrict__ glist,
        float* __restrict__ xg) {
    __shared__ float tile[64][65];
    __shared__ int nodes[64];
    int bx = blockIdx.x;
    if (bx < 1280) {                       // ---- coeff ----
        int s = bx >> 7, c = bx & 127;
        for (int t = threadIdx.x; t < NMONO * 4; t += 256) {
            int m = t >> 2, og = t & 3;
            float val;
            if (m < NCUB) {
                const float* W3 = (og == 0) ? W3_0e : W3_1o;   // [s][k][c]
                const float* u  = U3sym + (og * 165 + m) * 4;
                val = u[0] * W3[s*512 +       c] + u[1] * W3[s*512 + 128 + c]
                    + u[2] * W3[s*512 + 256 + c] + u[3] * W3[s*512 + 384 + c];
            } else if (m < NCUB + NQUAD) {
                int q = m - NCUB;
                const float* W2 = (og == 0) ? W2_0e : W2_1o;   // [s][k][c]
                const float* u  = U2sym + (og * 45 + q) * 2;
                val = u[0] * W2[s*256 + c] + u[1] * W2[s*256 + 128 + c];
            } else {
                int l = m - (NCUB + NQUAD);
                const float* U1 = (og == 0) ? U1_0e : U1_1o;   // [o][i][k=1]
                const float* W1 = (og == 0) ? W1_0e : W1_1o;   // [s][1][c]
                int o = (og == 0) ? 0 : og - 1;
                val = U1[o * 9 + l] * W1[s * 128 + c];
            }
            coeff[(size_t)bx * 876 + t] = val;
        }
        return;
    }
    // ---- gather ----
    int b2 = bx - 1280;
    int st = b2 / 18, ct = b2 - st * 18;   // slot-tile(64 slots), ci-tile(64 of 1152)
    int t = threadIdx.x;
    if (t < 64) nodes[t] = glist[st * 64 + t];
    __syncthreads();
    #pragma unroll
    for (int r = 0; r < 4; ++r) {          // 64 sl x 16 float4
        int flat = r * 256 + t;
        int sl = flat >> 4, q = flat & 15;
        float4 v = *(const float4*)&x[(size_t)nodes[sl] * 1152 + ct * 64 + q * 4];
        tile[sl][q * 4 + 0] = v.x; tile[sl][q * 4 + 1] = v.y;
        tile[sl][q * 4 + 2] = v.z; tile[sl][q * 4 + 3] = v.w;
    }
    __syncthreads();
    #pragma unroll
    for (int r = 0; r < 16; ++r) {
        int flat = r * 256 + t;
        int ci = flat >> 6, sl = flat & 63;
        xg[(size_t)(ct * 64 + ci) * 4096 + st * 64 + sl] = tile[sl][ci];
    }
}

// ---------------------------------------------------------------------------
// Kernel 5: main contraction. Block=(s,c), STRAIGHT-LINE single pass.
// History of this kernel's failure modes (do not regress):
//  - r2/r3/r5: LDS coeff reads inside a `for(base...)` loop -> LICM hoists
//    all 219 loop-invariant ds_read_b128 into the preheader (sched_barrier is
//    IntrNoMem, does NOT block IR-level LICM) -> 876 live VGPRs -> 1-2 GB
//    scratch spill, 7-9x regression. FIX: no loop at all. Species counts are
//    ~410 +- 40 << 512, so one 512-slot pass covers n; gridDim.y=2 guards the
//    (never-observed) n>512 case via uniformly-early-exiting y=1 blocks.
//  - r1/r4: coeffs via wave-uniform global pointer -> scalar s_load stream in
//    tiny batches, each waiting full L2 latency -> 141-180us latency-bound.
//  - r2: min-waves arg on __launch_bounds__ caps VGPR -> spill.
// Coeffs staged once to LDS (coalesced), read as uniform-address broadcasts;
// sched_barrier(0) per (a,b) group bounds machine-scheduler hoisting.
// ---------------------------------------------------------------------------
__global__ __launch_bounds__(256) void k_main(const float* __restrict__ xg,
        const int* __restrict__ cntoff, const float* __restrict__ coeff,
        float* __restrict__ fg) {
    __shared__ __align__(16) float cfs[880];
    int blk = blockIdx.x;
    int s = blk >> 7, c = blk & 127;
    int n = cntoff[s];
    int base = (int)blockIdx.y * 512;
    if (base >= n) return;                 // uniform early-out (y=1 blocks)
    const float* __restrict__ cf = coeff + (size_t)blk * 876;
    int t = threadIdx.x;
    if (t < 219) ((float4*)cfs)[t] = ((const float4*)cf)[t];
    int off = cntoff[16 + s];
    __syncthreads();

    int i0 = base + t;
    int i1 = i0 + 256;
    int j0 = off + min(i0, n - 1);
    int j1 = off + min(i1, n - 1);
    float x0[9], x1[9];
    #pragma unroll
    for (int i = 0; i < 9; i++) {
        const float* row = xg + (size_t)(c * 9 + i) * 4096;
        x0[i] = row[j0];
        x1[i] = row[j1];
    }
    float a0[4] = {0.f,0.f,0.f,0.f}, a1[4] = {0.f,0.f,0.f,0.f};
    int m3 = 0, m2 = 0;
    #pragma unroll
    for (int a = 0; a < 9; a++) {
        {   // linear term
            float4 cl = *(const float4*)&cfs[(210 + a) * 4];
            a0[0] = fmaf(cl.x, x0[a], a0[0]); a1[0] = fmaf(cl.x, x1[a], a1[0]);
            a0[1] = fmaf(cl.y, x0[a], a0[1]); a1[1] = fmaf(cl.y, x1[a], a1[1]);
            a0[2] = fmaf(cl.z, x0[a], a0[2]); a1[2] = fmaf(cl.z, x1[a], a1[2]);
            a0[3] = fmaf(cl.w, x0[a], a0[3]); a1[3] = fmaf(cl.w, x1[a], a1[3]);
        }
        #pragma unroll
        for (int b = a; b < 9; b++) {
            float p0 = x0[a] * x0[b], p1 = x1[a] * x1[b];
            float4 cq = *(const float4*)&cfs[(165 + m2) * 4]; m2++;
            a0[0] = fmaf(cq.x, p0, a0[0]); a1[0] = fmaf(cq.x, p1, a1[0]);
            a0[1] = fmaf(cq.y, p0, a0[1]); a1[1] = fmaf(cq.y, p1, a1[1]);
            a0[2] = fmaf(cq.z, p0, a0[2]); a1[2] = fmaf(cq.z, p1, a1[2]);
            a0[3] = fmaf(cq.w, p0, a0[3]); a1[3] = fmaf(cq.w, p1, a1[3]);
            #pragma unroll
            for (int d = b; d < 9; d++) {
                float4 c3 = *(const float4*)&cfs[m3 * 4]; m3++;
                float q0 = p0 * x0[d], q1 = p1 * x1[d];
                a0[0] = fmaf(c3.x, q0, a0[0]); a1[0] = fmaf(c3.x, q1, a1[0]);
                a0[1] = fmaf(c3.y, q0, a0[1]); a1[1] = fmaf(c3.y, q1, a1[1]);
                a0[2] = fmaf(c3.z, q0, a0[2]); a1[2] = fmaf(c3.z, q1, a1[2]);
                a0[3] = fmaf(c3.w, q0, a0[3]); a1[3] = fmaf(c3.w, q1, a1[3]);
            }
            __builtin_amdgcn_sched_barrier(0);  // bound scheduler hoisting
        }
    }
    if (i0 < n) {
        #pragma unroll
        for (int e = 0; e < 4; e++) fg[(size_t)(e * 128 + c) * 4096 + j0] = a0[e];
    }
    if (i1 < n) {
        #pragma unroll
        for (int e = 0; e < 4; e++) fg[(size_t)(e * 128 + c) * 4096 + j1] = a1[e];
    }
}

// ---------------------------------------------------------------------------
// Kernel 6: epilogue linear. Block=(slot-tile 64, jg 0..7); staging reads are
// fully coalesced from fg; output rows via glist (256B runs per row).
// ---------------------------------------------------------------------------
__global__ __launch_bounds__(256) void k_epi(const float* __restrict__ fg,
        const float* __restrict__ W0, const float* __restrict__ W1,
        const float* __restrict__ bias, const int* __restrict__ glist,
        float* __restrict__ out) {
    __shared__ float smem[128 * 65];
    __shared__ int nodes[64];
    int bx = blockIdx.x;
    int st = bx >> 3, jg = bx & 7;
    int s0 = st * 64;
    int t  = threadIdx.x;
    int o  = jg >> 1;                        // output component 0..3 (uniform)
    if (t < 64) nodes[t] = glist[s0 + t];
    #pragma unroll
    for (int r = 0; r < 32; ++r) {
        int flat = r * 256 + t;              // 8192 = 128c * 64sl
        int c = flat >> 6, sl = flat & 63;
        smem[c * 65 + sl] = fg[(size_t)(o * 128 + c) * 4096 + s0 + sl];
    }
    __syncthreads();

    int w    = __builtin_amdgcn_readfirstlane((int)(t >> 6));
    int lane = t & 63;
    int mb   = (jg & 1) * 64 + w * 16;       // wave's m base (uniform)
    const float* __restrict__ Wsel = (o == 0) ? W0 : W1;

    float acc[16];
    #pragma unroll
    for (int jj = 0; jj < 16; jj++) acc[jj] = 0.f;

    #pragma unroll 4
    for (int c = 0; c < 128; ++c) {
        float fv = smem[c * 65 + lane];
        #pragma unroll
        for (int jj = 0; jj < 16; jj++)
            acc[jj] = fmaf(fv, Wsel[c * 128 + mb + jj], acc[jj]);
    }
    __syncthreads();

    const float scale = 0.08838834764831845f; // 1/sqrt(128)
    #pragma unroll
    for (int jj = 0; jj < 16; jj++) {
        float v = acc[jj] * scale;
        if (o == 0) v += bias[mb + jj];
        smem[(w * 16 + jj) * 65 + lane] = v;  // trbuf[j_local][slot]
    }
    __syncthreads();

    #pragma unroll
    for (int r = 0; r < 16; ++r) {
        int flat = r * 256 + t;               // 4096 = 64j * 64sl
        int jl = flat & 63, nn = flat >> 6;
        int m  = (jg & 1) * 64 + jl;
        int col = (o == 0) ? m : (128 + m * 3 + (o - 1));
        out[(size_t)nodes[nn] * 512 + col] = smem[jl * 65 + nn];
    }
}

extern "C" void kernel_launch(void* const* d_in, const int* in_sizes, int n_in,
                              void* d_out, int out_size, void* d_ws, size_t ws_size,
                              hipStream_t stream) {
    const float* x     = (const float*)d_in[0];
    const int*   spec  = (const int*)  d_in[1];
    const float* U3_0e = (const float*)d_in[2];
    const float* U2_0e = (const float*)d_in[3];
    const float* U1_0e = (const float*)d_in[4];
    const float* W3_0e = (const float*)d_in[5];
    const float* W2_0e = (const float*)d_in[6];
    const float* W1_0e = (const float*)d_in[7];
    const float* U3_1o = (const float*)d_in[8];
    const float* U2_1o = (const float*)d_in[9];
    const float* U1_1o = (const float*)d_in[10];
    const float* W3_1o = (const float*)d_in[11];
    const float* W2_1o = (const float*)d_in[12];
    const float* W1_1o = (const float*)d_in[13];
    const float* Wlin0 = (const float*)d_in[14];
    const float* Wlin1 = (const float*)d_in[15];
    const float* bias0 = (const float*)d_in[16];
    float* out = (float*)d_out;

    char* ws = (char*)d_ws;
    int*   cntoff = (int*)  (ws + WS_CNTOFF);
    int*   glist  = (int*)  (ws + WS_GLIST);
    float* U3sym  = (float*)(ws + WS_U3SYM);
    float* U2sym  = (float*)(ws + WS_U2SYM);
    float* coeff  = (float*)(ws + WS_COEFF);
    float* xg     = (float*)(ws + WS_XG);
    float* fg     = (float*)(ws + WS_FG);
    (void)in_sizes; (void)n_in; (void)out_size; (void)ws_size;

    hipLaunchKernelGGL(k_a,    dim3(9),       dim3(512), 0, stream,
                       U3_0e, U3_1o, U2_0e, U2_1o, spec, cntoff, glist, U3sym, U2sym);
    hipLaunchKernelGGL(k_b,    dim3(2432),    dim3(256), 0, stream,
                       U3sym, U2sym, U1_0e, U1_1o, W3_0e, W3_1o,
                       W2_0e, W2_1o, W1_0e, W1_1o, coeff, x, glist, xg);
    hipLaunchKernelGGL(k_main, dim3(1280, 2), dim3(256), 0, stream, xg, cntoff, coeff, fg);
    hipLaunchKernelGGL(k_epi,  dim3(512),     dim3(256), 0, stream, fg, Wlin0, Wlin1, bias0, glist, out);
}